// Round 8
// baseline (169.724 us; speedup 1.0000x reference)
//
#include <hip/hip_runtime.h>
#include <stdint.h>

// CategoricalEncoder: out[b,t,n,:] = codebook[n, argmax_s(logits + gumbel), :]
// Reproduces jax.random.categorical(jax.random.key(42), logits) under the
// MODERN (jax_threefry_partitionable=True, default since JAX 0.4.36) bit
// semantics: element i's random bits = o0 ^ o1 where
// (o0,o1) = threefry2x32(key=(0,42), counts=(0, i)).
//
// uniform: f = bitcast((bits>>9)|0x3F800000) - 1.0 in [0,1);
//          u = max(tiny, f*1.0 + tiny) == (f>0 ? f : FLT_MIN) in f32.
// gumbel = -log(-log(u)); sample idx = argmax_s(gumbel + logit), first-index
// tiebreak. Straight-through term (sample + probs - stop_grad(probs)) equals
// one_hot(idx)*(1+delta), |delta|<=1.2e-7 -> output = codebook row gather.

#define STOCH 32
#define EMBED 128

__device__ __forceinline__ uint32_t rotl32(uint32_t x, int r) {
  return (x << r) | (x >> (32 - r));
}

// threefry2x32, 20 rounds, key=(0,42), counts=(0,i); returns o0^o1.
__device__ __forceinline__ uint32_t threefry_bits_0_42(uint32_t i) {
  const uint32_t k0 = 0u;
  const uint32_t k1 = 42u;
  const uint32_t k2 = 0x1BD11BDAu ^ k0 ^ k1;  // 0x1BD11BF0

  uint32_t x0 = k0;        // counts1 = 0, + k0
  uint32_t x1 = i + k1;    // counts2 = i, + k1
  // rounds 1-4: [13,15,26,6]
  x0 += x1; x1 = rotl32(x1, 13); x1 ^= x0;
  x0 += x1; x1 = rotl32(x1, 15); x1 ^= x0;
  x0 += x1; x1 = rotl32(x1, 26); x1 ^= x0;
  x0 += x1; x1 = rotl32(x1,  6); x1 ^= x0;
  x0 += k1; x1 += k2 + 1u;
  // rounds 5-8: [17,29,16,24]
  x0 += x1; x1 = rotl32(x1, 17); x1 ^= x0;
  x0 += x1; x1 = rotl32(x1, 29); x1 ^= x0;
  x0 += x1; x1 = rotl32(x1, 16); x1 ^= x0;
  x0 += x1; x1 = rotl32(x1, 24); x1 ^= x0;
  x0 += k2; x1 += k0 + 2u;
  // rounds 9-12: [13,15,26,6]
  x0 += x1; x1 = rotl32(x1, 13); x1 ^= x0;
  x0 += x1; x1 = rotl32(x1, 15); x1 ^= x0;
  x0 += x1; x1 = rotl32(x1, 26); x1 ^= x0;
  x0 += x1; x1 = rotl32(x1,  6); x1 ^= x0;
  x0 += k0; x1 += k1 + 3u;
  // rounds 13-16: [17,29,16,24]
  x0 += x1; x1 = rotl32(x1, 17); x1 ^= x0;
  x0 += x1; x1 = rotl32(x1, 29); x1 ^= x0;
  x0 += x1; x1 = rotl32(x1, 16); x1 ^= x0;
  x0 += x1; x1 = rotl32(x1, 24); x1 ^= x0;
  x0 += k1; x1 += k2 + 4u;
  // rounds 17-20: [13,15,26,6]
  x0 += x1; x1 = rotl32(x1, 13); x1 ^= x0;
  x0 += x1; x1 = rotl32(x1, 15); x1 ^= x0;
  x0 += x1; x1 = rotl32(x1, 26); x1 ^= x0;
  x0 += x1; x1 = rotl32(x1,  6); x1 ^= x0;
  x0 += k2; x1 += k0 + 5u;

  return x0 ^ x1;
}

__device__ __forceinline__ float bits_to_gumbel(uint32_t bits) {
  float f = __uint_as_float((bits >> 9) | 0x3F800000u) - 1.0f;
  float u = (f > 0.0f) ? f : 1.17549435e-38f;  // FLT_MIN (jnp.finfo.tiny)
  return -logf(-logf(u));
}

__global__ __launch_bounds__(256) void CategoricalEncoder_kernel(
    const float* __restrict__ x, const float* __restrict__ cb,
    float* __restrict__ out) {
  __shared__ int s_idx[8];

  const int tid = threadIdx.x;
  const int g = tid >> 5;            // half-wave id [0,8): one triple each
  const int s = tid & 31;            // class lane
  const unsigned tau = blockIdx.x * 8u + (unsigned)g;  // triple (b,t,n)
  const unsigned i = tau * 32u + (unsigned)s;          // elem in [B,T,N,S]

  uint32_t bits = threefry_bits_0_42(i);
  float v = bits_to_gumbel(bits) + x[i];

  // argmax over 32 lanes, first-index tiebreak (matches jnp.argmax)
  int idx = s;
#pragma unroll
  for (int m = 16; m >= 1; m >>= 1) {
    float w = __shfl_xor(v, m, 32);
    int j = __shfl_xor(idx, m, 32);
    if (w > v || (w == v && j < idx)) { v = w; idx = j; }
  }
  if (s == 0) s_idx[g] = idx;
  __syncthreads();

  // Phase 2: one float4 per thread; out/x both stride base + tid (coalesced).
  const float4* cb4 = reinterpret_cast<const float4*>(cb);
  float4* out4 = reinterpret_cast<float4*>(out);
  const unsigned trip = (unsigned)tid >> 5;
  const unsigned q = (unsigned)tid & 31u;       // float4 index in 128-f row
  const unsigned tau2 = blockIdx.x * 8u + trip;
  const unsigned n = tau2 & 31u;                // fastest triple dim is n
  const unsigned row = (unsigned)s_idx[trip];
  out4[tau2 * 32u + q] = cb4[(n * STOCH + row) * (EMBED / 4) + q];
}

extern "C" void kernel_launch(void* const* d_in, const int* in_sizes, int n_in,
                              void* d_out, int out_size, void* d_ws,
                              size_t ws_size, hipStream_t stream) {
  const float* x = (const float*)d_in[0];   // [32,256,1024] f32
  const float* cb = (const float*)d_in[1];  // [32,32,128] f32
  float* out = (float*)d_out;               // [32,256,4096] f32
  (void)in_sizes; (void)n_in; (void)out_size; (void)d_ws; (void)ws_size;

  dim3 grid(32768), block(256);
  hipLaunchKernelGGL(CategoricalEncoder_kernel, grid, block, 0, stream,
                     x, cb, out);
}

// Round 9
// 166.859 us; speedup vs baseline: 1.0172x; 1.0172x over previous
//
#include <hip/hip_runtime.h>
#include <stdint.h>

// CategoricalEncoder: out[b,t,n,:] = codebook[n, argmax_s(logits + gumbel), :]
// Reproduces jax.random.categorical(jax.random.key(42), logits) under modern
// (jax_threefry_partitionable=True) semantics: element i's bits = o0 ^ o1 of
// threefry2x32(key=(0,42), counts=(0,i)).  VERIFIED round 8: absmax 9.8e-4.
//
// This revision: no LDS / no __syncthreads (butterfly leaves group-argmax in
// every lane; phase-2 grouping == phase-1 grouping), and argmax via value-only
// max butterfly (5 shuffles) + ballot/ffs first-index tiebreak (was 10
// shuffles + cndmask chain).

#define STOCH 32
#define EMBED 128

__device__ __forceinline__ uint32_t rotl32(uint32_t x, int r) {
  return (x << r) | (x >> (32 - r));
}

// threefry2x32, 20 rounds, key=(0,42), counts=(0,i); returns o0^o1.
__device__ __forceinline__ uint32_t threefry_bits_0_42(uint32_t i) {
  const uint32_t k0 = 0u;
  const uint32_t k1 = 42u;
  const uint32_t k2 = 0x1BD11BDAu ^ k0 ^ k1;  // 0x1BD11BF0

  uint32_t x0 = k0;        // counts1 = 0, + k0
  uint32_t x1 = i + k1;    // counts2 = i, + k1
  // rounds 1-4: [13,15,26,6]
  x0 += x1; x1 = rotl32(x1, 13); x1 ^= x0;
  x0 += x1; x1 = rotl32(x1, 15); x1 ^= x0;
  x0 += x1; x1 = rotl32(x1, 26); x1 ^= x0;
  x0 += x1; x1 = rotl32(x1,  6); x1 ^= x0;
  x0 += k1; x1 += k2 + 1u;
  // rounds 5-8: [17,29,16,24]
  x0 += x1; x1 = rotl32(x1, 17); x1 ^= x0;
  x0 += x1; x1 = rotl32(x1, 29); x1 ^= x0;
  x0 += x1; x1 = rotl32(x1, 16); x1 ^= x0;
  x0 += x1; x1 = rotl32(x1, 24); x1 ^= x0;
  x0 += k2; x1 += k0 + 2u;
  // rounds 9-12: [13,15,26,6]
  x0 += x1; x1 = rotl32(x1, 13); x1 ^= x0;
  x0 += x1; x1 = rotl32(x1, 15); x1 ^= x0;
  x0 += x1; x1 = rotl32(x1, 26); x1 ^= x0;
  x0 += x1; x1 = rotl32(x1,  6); x1 ^= x0;
  x0 += k0; x1 += k1 + 3u;
  // rounds 13-16: [17,29,16,24]
  x0 += x1; x1 = rotl32(x1, 17); x1 ^= x0;
  x0 += x1; x1 = rotl32(x1, 29); x1 ^= x0;
  x0 += x1; x1 = rotl32(x1, 16); x1 ^= x0;
  x0 += x1; x1 = rotl32(x1, 24); x1 ^= x0;
  x0 += k1; x1 += k2 + 4u;
  // rounds 17-20: [13,15,26,6]
  x0 += x1; x1 = rotl32(x1, 13); x1 ^= x0;
  x0 += x1; x1 = rotl32(x1, 15); x1 ^= x0;
  x0 += x1; x1 = rotl32(x1, 26); x1 ^= x0;
  x0 += x1; x1 = rotl32(x1,  6); x1 ^= x0;
  x0 += k2; x1 += k0 + 5u;

  return x0 ^ x1;
}

__device__ __forceinline__ float bits_to_gumbel(uint32_t bits) {
  float f = __uint_as_float((bits >> 9) | 0x3F800000u) - 1.0f;
  float u = (f > 0.0f) ? f : 1.17549435e-38f;  // FLT_MIN (jnp.finfo.tiny)
  return -logf(-logf(u));
}

__global__ __launch_bounds__(256) void CategoricalEncoder_kernel(
    const float* __restrict__ x, const float* __restrict__ cb,
    float* __restrict__ out) {
  const int tid = threadIdx.x;
  const int s = tid & 31;                              // class lane
  const unsigned tau = blockIdx.x * 8u + ((unsigned)tid >> 5);  // (b,t,n)
  const unsigned i = tau * 32u + (unsigned)s;          // elem in [B,T,N,S]

  const float xi = x[i];                     // issue early; hides under threefry
  const uint32_t bits = threefry_bits_0_42(i);
  const float v0 = bits_to_gumbel(bits) + xi;

  // group max (butterfly leaves result in ALL lanes of the 32-group)
  float v = v0;
#pragma unroll
  for (int m = 16; m >= 1; m >>= 1) v = fmaxf(v, __shfl_xor(v, m, 32));

  // first-index tiebreak: lowest lane in this 32-group whose v0 == group max.
  // No NaNs possible (u in [FLT_MIN,1) => gumbel finite; x finite).
  const unsigned long long mask = __ballot(v0 == v);
  const uint32_t m32 = (uint32_t)(mask >> ((tid & 32)));  // this group's half
  const uint32_t idx = (uint32_t)(__ffs(m32) - 1);

  // gather-write: this thread writes float4 #s of its own triple's row.
  const float4* cb4 = reinterpret_cast<const float4*>(cb);
  float4* out4 = reinterpret_cast<float4*>(out);
  const uint32_t n = tau & 31u;              // fastest triple dim is n
  out4[tau * 32u + (unsigned)s] = cb4[n * 1024u + idx * 32u + (unsigned)s];
}

extern "C" void kernel_launch(void* const* d_in, const int* in_sizes, int n_in,
                              void* d_out, int out_size, void* d_ws,
                              size_t ws_size, hipStream_t stream) {
  const float* x = (const float*)d_in[0];   // [32,256,1024] f32
  const float* cb = (const float*)d_in[1];  // [32,32,128] f32
  float* out = (float*)d_out;               // [32,256,4096] f32
  (void)in_sizes; (void)n_in; (void)out_size; (void)d_ws; (void)ws_size;

  dim3 grid(32768), block(256);
  hipLaunchKernelGGL(CategoricalEncoder_kernel, grid, block, 0, stream,
                     x, cb, out);
}